// Round 14
// baseline (418.869 us; speedup 1.0000x reference)
//
#include <hip/hip_runtime.h>
#include <hip/hip_bf16.h>
#include <math.h>

#define N_ROWS 65536
#define PSI    1024
#define DDIM   256
#define NBLK   1024

typedef _Float16       half8 __attribute__((ext_vector_type(8)));
typedef _Float16       half4 __attribute__((ext_vector_type(4)));
typedef float          f32x4 __attribute__((ext_vector_type(4)));

// ---------- async global->LDS, 16B per lane ----------
__device__ __forceinline__ void gload16(const void* g, void* l) {
    __builtin_amdgcn_global_load_lds(
        (const __attribute__((address_space(1))) unsigned int*)g,
        (__attribute__((address_space(3))) unsigned int*)l, 16, 0, 0);
}

// ---------- fused convert (X and S) + row norms + stats init ----------
// blocks [0,16384): X rows; [16384,16640): S rows; block 16640: init.
__global__ __launch_bounds__(256) void k_convert_all(
    const float* __restrict__ X, const float* __restrict__ S,
    _Float16* __restrict__ Xh, _Float16* __restrict__ Sh,
    float* __restrict__ x2, float* __restrict__ s2,
    float* __restrict__ gsum, unsigned* __restrict__ done)
{
    const int bid = blockIdx.x;
    if (bid == 16640) {                      // init gsum + done each call
        for (int i = threadIdx.x; i < PSI; i += 256) gsum[i] = 0.0f;
        if (threadIdx.x == 0) *done = 0u;
        return;
    }
    const float* in; _Float16* outh; float* nrm; int row;
    const int wib  = threadIdx.x >> 6;
    const int lane = threadIdx.x & 63;
    if (bid < 16384) { in = X; outh = Xh; nrm = x2; row = bid * 4 + wib; }
    else { in = S; outh = Sh; nrm = s2; row = (bid - 16384) * 4 + wib; }
    const float4 v = *(const float4*)&in[(size_t)row * DDIM + lane * 4];
    float s = v.x * v.x + v.y * v.y + v.z * v.z + v.w * v.w;
    #pragma unroll
    for (int o = 32; o > 0; o >>= 1) s += __shfl_down(s, o);
    if (lane == 0) nrm[row] = s;
    half4 h;
    h[0] = (_Float16)v.x; h[1] = (_Float16)v.y;
    h[2] = (_Float16)v.z; h[3] = (_Float16)v.w;
    *(half4*)&outh[(size_t)row * DDIM + lane * 4] = h;
}

// ---------- persistent fused GEMM: phase1 sums -> grid spin -> phase2 out ---
// Grid 1024 = exact residency: launch_bounds(256,4) + 32 KB LDS -> 4
// blocks/CU x 256 CU. Each block owns 4 tiles (same XCD-chunked map as the
// 4096-grid version: XCD (b&7) owns 64 contiguous row-panels x 8 cols).
// Per tile: R10's proven BK=32 double-buffered K-loop (swizzle chunk ^=
// (row>>1)&3 both-sides; 2-way banks = free). Phase 1 epilogue accumulates
// column sums of u = exp(-m) directly into global gsum (absorbs the combine
// kernels). Device-scope done-counter spin = grid barrier (all blocks
// resident by construction). Phase 2 recomputes (panels L2-hot) and writes
// out = u / gsum[c] via NT stores. Shift-free softmax: u in [1e-13,1].
__global__ __launch_bounds__(256, 4) void k_fused(
    const _Float16* __restrict__ Xh, const _Float16* __restrict__ Sh,
    const float* __restrict__ x2, const float* __restrict__ s2,
    const float* __restrict__ w,
    float* __restrict__ gsum, unsigned* __restrict__ done,
    float* __restrict__ out)
{
    __shared__ _Float16 As[2][128 * 32];   // 2 x 8 KB
    __shared__ _Float16 Bs[2][128 * 32];   // 2 x 8 KB

    const int tid = threadIdx.x;
    const int wv  = tid >> 6;
    const int wr  = wv >> 1;
    const int wc  = wv & 1;
    const int l15 = tid & 15;
    const int l4  = (tid & 63) >> 4;
    const int bk  = blockIdx.x;

    const int srow = tid >> 2;              // 0..63
    const int skq  = ((tid & 3) ^ ((srow >> 1) & 3)) * 8;

    // one tile: GEMM into acc, then mode epilogue (0: gsum, 1: out)
    auto run_tile = [&](int wgid, int mode) {
        const int rowb = wgid >> 3;
        const int row0 = rowb * 128;
        const int col0 = (wgid & 7) * 128;

        const _Float16* gAp = Xh + (size_t)(row0 + srow) * DDIM + skq;
        const _Float16* gBp = Sh + (size_t)(col0 + srow) * DDIM + skq;

        f32x4 acc[4][4];
        #pragma unroll
        for (int i = 0; i < 4; ++i)
            #pragma unroll
            for (int j = 0; j < 4; ++j) acc[i][j] = (f32x4){0.f, 0.f, 0.f, 0.f};

        auto stage = [&](int k0, int b) {
            _Float16* Ab = &As[b][wv * 512];
            _Float16* Bb = &Bs[b][wv * 512];
            #pragma unroll
            for (int rg = 0; rg < 2; ++rg)
                gload16(gAp + (size_t)(rg * 64) * DDIM + k0, Ab + rg * 2048);
            #pragma unroll
            for (int rg = 0; rg < 2; ++rg)
                gload16(gBp + (size_t)(rg * 64) * DDIM + k0, Bb + rg * 2048);
        };
        auto compute = [&](int t) {
            const int b = t & 1;
            half8 af[4], bf[4];
            #pragma unroll
            for (int f = 0; f < 4; ++f) {
                const int ra = wr * 64 + f * 16 + l15;
                const int rb = wc * 64 + f * 16 + l15;
                const int ha = (ra * 32 + l4 * 8) ^ (((ra >> 1) & 3) << 3);
                const int hb = (rb * 32 + l4 * 8) ^ (((rb >> 1) & 3) << 3);
                af[f] = *(const half8*)&As[b][ha];
                bf[f] = *(const half8*)&Bs[b][hb];
            }
            #pragma unroll
            for (int fm = 0; fm < 4; ++fm)
                #pragma unroll
                for (int fn = 0; fn < 4; ++fn)
                    acc[fm][fn] = __builtin_amdgcn_mfma_f32_16x16x32_f16(
                        af[fm], bf[fn], acc[fm][fn], 0, 0, 0);
        };

        __syncthreads();                    // prior tile's LDS use finished
        stage(0, 0);
        __syncthreads();
        #pragma unroll
        for (int t = 0; t < 8; ++t) {       // K = 8 x 32
            if (t < 7) stage((t + 1) * 32, (t + 1) & 1);
            compute(t);
            if (t < 7) __syncthreads();
        }

        float4 x2r[4];
        #pragma unroll
        for (int fm = 0; fm < 4; ++fm)
            x2r[fm] = *(const float4*)&x2[row0 + wr * 64 + fm * 16 + l4 * 4];

        if (mode == 0) {
            __syncthreads();                // As dead -> alias sum array
            float* s_sm = (float*)&As[0][0];
            if (tid < 128) s_sm[tid] = 0.0f;
            __syncthreads();
            #pragma unroll
            for (int fn = 0; fn < 4; ++fn) {
                const int cl = wc * 64 + fn * 16 + l15;
                const int c  = col0 + cl;
                const float s2c = s2[c], ww = w[c];
                float s = 0.0f;
                #pragma unroll
                for (int fm = 0; fm < 4; ++fm) {
                    const float* xr = (const float*)&x2r[fm];
                    #pragma unroll
                    for (int j = 0; j < 4; ++j) {
                        float d2 = xr[j] + s2c - 2.0f * acc[fm][fn][j];
                        s += __expf(-sqrtf(fmaxf(d2, 0.0f)) * ww);
                    }
                }
                s += __shfl_xor(s, 16);
                s += __shfl_xor(s, 32);
                if (l4 == 0) atomicAdd(&s_sm[cl], s);
            }
            __syncthreads();
            if (tid < 128) atomicAdd(&gsum[col0 + tid], s_sm[tid]);
        } else {
            #pragma unroll
            for (int fn = 0; fn < 4; ++fn) {
                const int c = col0 + wc * 64 + fn * 16 + l15;
                const float s2c = s2[c], ww = w[c];
                const float g = __hip_atomic_load(&gsum[c], __ATOMIC_RELAXED,
                                                  __HIP_MEMORY_SCOPE_AGENT);
                const float rsc = 1.0f / g;
                #pragma unroll
                for (int fm = 0; fm < 4; ++fm) {
                    const float* xr = (const float*)&x2r[fm];
                    const int rbase = row0 + wr * 64 + fm * 16 + l4 * 4;
                    #pragma unroll
                    for (int j = 0; j < 4; ++j) {
                        float d2 = xr[j] + s2c - 2.0f * acc[fm][fn][j];
                        float u  = __expf(-sqrtf(fmaxf(d2, 0.0f)) * ww) * rsc;
                        __builtin_nontemporal_store(u,
                            &out[(size_t)(rbase + j) * PSI + c]);
                    }
                }
            }
        }
    };

    // ---- phase 1: column sums for my 4 tiles ----
    #pragma unroll 1
    for (int k = 0; k < 4; ++k)
        run_tile((bk & 7) * 512 + (bk >> 3) + k * 128, 0);

    // ---- grid barrier: all 1024 blocks resident by construction ----
    __syncthreads();                        // drains this block's atomics
    if (tid == 0) {
        __threadfence();                    // release gsum updates
        __hip_atomic_fetch_add(done, 1u, __ATOMIC_ACQ_REL,
                               __HIP_MEMORY_SCOPE_AGENT);
        while (__hip_atomic_load(done, __ATOMIC_ACQUIRE,
                                 __HIP_MEMORY_SCOPE_AGENT) < NBLK)
            __builtin_amdgcn_s_sleep(32);
    }
    __syncthreads();

    // ---- phase 2: recompute + scaled write (panels L2-hot) ----
    #pragma unroll 1
    for (int k = 0; k < 4; ++k)
        run_tile((bk & 7) * 512 + (bk >> 3) + k * 128, 1);
}

extern "C" void kernel_launch(void* const* d_in, const int* in_sizes, int n_in,
                              void* d_out, int out_size, void* d_ws, size_t ws_size,
                              hipStream_t stream) {
    const float* X = (const float*)d_in[0];
    const float* S = (const float*)d_in[1];
    const float* w = (const float*)d_in[2];
    float* out = (float*)d_out;

    char* ws = (char*)d_ws;
    _Float16* Xh   = (_Float16*)(ws);                  // 33,554,432 B
    _Float16* Sh   = (_Float16*)(ws + 33554432);       //    524,288 B
    float*    x2   = (float*)   (ws + 34078720);       //    262,144 B
    float*    s2   = (float*)   (ws + 34340864);       //      4,096 B
    float*    gsum = (float*)   (ws + 34344960);       //      4,096 B
    unsigned* done = (unsigned*)(ws + 34349056);       //      4,096 B

    k_convert_all<<<dim3(16641), dim3(256), 0, stream>>>(
        X, S, Xh, Sh, x2, s2, gsum, done);
    k_fused<<<dim3(NBLK), dim3(256), 0, stream>>>(
        Xh, Sh, x2, s2, w, gsum, done, out);
}

// Round 15
// 215.373 us; speedup vs baseline: 1.9449x; 1.9449x over previous
//
#include <hip/hip_runtime.h>
#include <hip/hip_bf16.h>
#include <math.h>
#include <utility>

#define N_ROWS 65536
#define PSI    1024
#define DDIM   256
#define NBLK   512

typedef _Float16       half8 __attribute__((ext_vector_type(8)));
typedef _Float16       half4 __attribute__((ext_vector_type(4)));
typedef float          f32x4 __attribute__((ext_vector_type(4)));

// ---------- async global->LDS, 16B per lane ----------
__device__ __forceinline__ void gload16(const void* g, void* l) {
    __builtin_amdgcn_global_load_lds(
        (const __attribute__((address_space(1))) unsigned int*)g,
        (__attribute__((address_space(3))) unsigned int*)l, 16, 0, 0);
}

// ---------- fused convert (X and S) + row norms + stats init ----------
// blocks [0,16384): X rows; [16384,16640): S rows; block 16640: init.
__global__ __launch_bounds__(256) void k_convert_all(
    const float* __restrict__ X, const float* __restrict__ S,
    _Float16* __restrict__ Xh, _Float16* __restrict__ Sh,
    float* __restrict__ x2, float* __restrict__ s2,
    float* __restrict__ gsum, unsigned* __restrict__ done)
{
    const int bid = blockIdx.x;
    if (bid == 16640) {                      // init gsum + done each call
        for (int i = threadIdx.x; i < PSI; i += 256) gsum[i] = 0.0f;
        if (threadIdx.x == 0) *done = 0u;
        return;
    }
    const float* in; _Float16* outh; float* nrm; int row;
    const int wib  = threadIdx.x >> 6;
    const int lane = threadIdx.x & 63;
    if (bid < 16384) { in = X; outh = Xh; nrm = x2; row = bid * 4 + wib; }
    else { in = S; outh = Sh; nrm = s2; row = (bid - 16384) * 4 + wib; }
    const float4 v = *(const float4*)&in[(size_t)row * DDIM + lane * 4];
    float s = v.x * v.x + v.y * v.y + v.z * v.z + v.w * v.w;
    #pragma unroll
    for (int o = 32; o > 0; o >>= 1) s += __shfl_down(s, o);
    if (lane == 0) nrm[row] = s;
    half4 h;
    h[0] = (_Float16)v.x; h[1] = (_Float16)v.y;
    h[2] = (_Float16)v.z; h[3] = (_Float16)v.w;
    *(half4*)&outh[(size_t)row * DDIM + lane * 4] = h;
}

// ---------- persistent fused GEMM: phase1 sums -> grid spin -> phase2 out ---
// Grid 512 = guaranteed residency: launch_bounds(256,2) caps nothing below
// the kernel's ~110 VGPR need (R14's (256,4) forced a 64-VGPR cap -> scratch
// spills, FETCH 253MB, 2.6x regression) and guarantees >=2 blocks/CU; 512
// blocks are resident even at that minimum (natural occupancy 4/CU).
// Each block owns 8 tiles, K-MAJOR chunked: tile k of block bk is
// wgid = xcd*512 + k*64 + (bk>>3) -> the 64 concurrent blocks of an XCD
// cover 8 row-panels x 8 cols (~1MB) per k-step, well inside 4MB L2.
// Tile body = R10's proven BK=32 double-buffered loop (swizzle chunk ^=
// (row>>1)&3 both-sides). Phase 1: column sums of u=exp(-m) -> global
// atomics (absorbs combine kernels). Device-scope done-counter spin = grid
// barrier. Phase 2: recompute, out = u/gsum[c], NT stores.
// Shift-free softmax: u in [1e-13,1] -> no max-shift needed.
__global__ __launch_bounds__(256, 2) void k_fused(
    const _Float16* __restrict__ Xh, const _Float16* __restrict__ Sh,
    const float* __restrict__ x2, const float* __restrict__ s2,
    const float* __restrict__ w,
    float* __restrict__ gsum, unsigned* __restrict__ done,
    float* __restrict__ out)
{
    __shared__ _Float16 As[2][128 * 32];   // 2 x 8 KB
    __shared__ _Float16 Bs[2][128 * 32];   // 2 x 8 KB

    const int tid = threadIdx.x;
    const int wv  = tid >> 6;
    const int wr  = wv >> 1;
    const int wc  = wv & 1;
    const int l15 = tid & 15;
    const int l4  = (tid & 63) >> 4;
    const int bk  = blockIdx.x;
    const int xcd = bk & 7;
    const int jj  = bk >> 3;                // 0..63

    const int srow = tid >> 2;              // 0..63
    const int skq  = ((tid & 3) ^ ((srow >> 1) & 3)) * 8;

    // one tile: GEMM into acc, then mode epilogue (0: gsum, 1: out)
    auto run_tile = [&](int wgid, auto mode_c) {
        constexpr int mode = decltype(mode_c)::value;
        const int rowb = wgid >> 3;
        const int row0 = rowb * 128;
        const int col0 = (wgid & 7) * 128;

        const _Float16* gAp = Xh + (size_t)(row0 + srow) * DDIM + skq;
        const _Float16* gBp = Sh + (size_t)(col0 + srow) * DDIM + skq;

        f32x4 acc[4][4];
        #pragma unroll
        for (int i = 0; i < 4; ++i)
            #pragma unroll
            for (int j = 0; j < 4; ++j) acc[i][j] = (f32x4){0.f, 0.f, 0.f, 0.f};

        auto stage = [&](int k0, int b) {
            _Float16* Ab = &As[b][wv * 512];
            _Float16* Bb = &Bs[b][wv * 512];
            #pragma unroll
            for (int rg = 0; rg < 2; ++rg)
                gload16(gAp + (size_t)(rg * 64) * DDIM + k0, Ab + rg * 2048);
            #pragma unroll
            for (int rg = 0; rg < 2; ++rg)
                gload16(gBp + (size_t)(rg * 64) * DDIM + k0, Bb + rg * 2048);
        };
        auto compute = [&](int t) {
            const int b = t & 1;
            half8 af[4], bf[4];
            #pragma unroll
            for (int f = 0; f < 4; ++f) {
                const int ra = wr * 64 + f * 16 + l15;
                const int rb = wc * 64 + f * 16 + l15;
                const int ha = (ra * 32 + l4 * 8) ^ (((ra >> 1) & 3) << 3);
                const int hb = (rb * 32 + l4 * 8) ^ (((rb >> 1) & 3) << 3);
                af[f] = *(const half8*)&As[b][ha];
                bf[f] = *(const half8*)&Bs[b][hb];
            }
            #pragma unroll
            for (int fm = 0; fm < 4; ++fm)
                #pragma unroll
                for (int fn = 0; fn < 4; ++fn)
                    acc[fm][fn] = __builtin_amdgcn_mfma_f32_16x16x32_f16(
                        af[fm], bf[fn], acc[fm][fn], 0, 0, 0);
        };

        __syncthreads();                    // prior tile's LDS use finished
        stage(0, 0);
        __syncthreads();
        #pragma unroll
        for (int t = 0; t < 8; ++t) {       // K = 8 x 32
            if (t < 7) stage((t + 1) * 32, (t + 1) & 1);
            compute(t);
            if (t < 7) __syncthreads();
        }

        float4 x2r[4];
        #pragma unroll
        for (int fm = 0; fm < 4; ++fm)
            x2r[fm] = *(const float4*)&x2[row0 + wr * 64 + fm * 16 + l4 * 4];

        if constexpr (mode == 0) {
            __syncthreads();                // As dead -> alias sum array
            float* s_sm = (float*)&As[0][0];
            if (tid < 128) s_sm[tid] = 0.0f;
            __syncthreads();
            #pragma unroll
            for (int fn = 0; fn < 4; ++fn) {
                const int cl = wc * 64 + fn * 16 + l15;
                const int c  = col0 + cl;
                const float s2c = s2[c], ww = w[c];
                float s = 0.0f;
                #pragma unroll
                for (int fm = 0; fm < 4; ++fm) {
                    const float* xr = (const float*)&x2r[fm];
                    #pragma unroll
                    for (int j = 0; j < 4; ++j) {
                        float d2 = xr[j] + s2c - 2.0f * acc[fm][fn][j];
                        s += __expf(-sqrtf(fmaxf(d2, 0.0f)) * ww);
                    }
                }
                s += __shfl_xor(s, 16);
                s += __shfl_xor(s, 32);
                if (l4 == 0) atomicAdd(&s_sm[cl], s);
            }
            __syncthreads();
            if (tid < 128) atomicAdd(&gsum[col0 + tid], s_sm[tid]);
        } else {
            #pragma unroll
            for (int fn = 0; fn < 4; ++fn) {
                const int c = col0 + wc * 64 + fn * 16 + l15;
                const float s2c = s2[c], ww = w[c];
                const float g = __hip_atomic_load(&gsum[c], __ATOMIC_RELAXED,
                                                  __HIP_MEMORY_SCOPE_AGENT);
                const float rsc = 1.0f / g;
                #pragma unroll
                for (int fm = 0; fm < 4; ++fm) {
                    const float* xr = (const float*)&x2r[fm];
                    const int rbase = row0 + wr * 64 + fm * 16 + l4 * 4;
                    #pragma unroll
                    for (int j = 0; j < 4; ++j) {
                        float d2 = xr[j] + s2c - 2.0f * acc[fm][fn][j];
                        float u  = __expf(-sqrtf(fmaxf(d2, 0.0f)) * ww) * rsc;
                        __builtin_nontemporal_store(u,
                            &out[(size_t)(rbase + j) * PSI + c]);
                    }
                }
            }
        }
    };

    // ---- phase 1: column sums for my 8 tiles (k-major chunks) ----
    #pragma unroll 1
    for (int k = 0; k < 8; ++k)
        run_tile(xcd * 512 + k * 64 + jj, std::integral_constant<int, 0>{});

    // ---- grid barrier: all 512 blocks resident by construction ----
    __syncthreads();                        // block's atomics issued
    if (tid == 0) {
        __threadfence();                    // release gsum updates
        __hip_atomic_fetch_add(done, 1u, __ATOMIC_ACQ_REL,
                               __HIP_MEMORY_SCOPE_AGENT);
        while (__hip_atomic_load(done, __ATOMIC_ACQUIRE,
                                 __HIP_MEMORY_SCOPE_AGENT) < NBLK)
            __builtin_amdgcn_s_sleep(32);
    }
    __syncthreads();

    // ---- phase 2: recompute + scaled write ----
    #pragma unroll 1
    for (int k = 0; k < 8; ++k)
        run_tile(xcd * 512 + k * 64 + jj, std::integral_constant<int, 1>{});
}

extern "C" void kernel_launch(void* const* d_in, const int* in_sizes, int n_in,
                              void* d_out, int out_size, void* d_ws, size_t ws_size,
                              hipStream_t stream) {
    const float* X = (const float*)d_in[0];
    const float* S = (const float*)d_in[1];
    const float* w = (const float*)d_in[2];
    float* out = (float*)d_out;

    char* ws = (char*)d_ws;
    _Float16* Xh   = (_Float16*)(ws);                  // 33,554,432 B
    _Float16* Sh   = (_Float16*)(ws + 33554432);       //    524,288 B
    float*    x2   = (float*)   (ws + 34078720);       //    262,144 B
    float*    s2   = (float*)   (ws + 34340864);       //      4,096 B
    float*    gsum = (float*)   (ws + 34344960);       //      4,096 B
    unsigned* done = (unsigned*)(ws + 34349056);       //      4,096 B

    k_convert_all<<<dim3(16641), dim3(256), 0, stream>>>(
        X, S, Xh, Sh, x2, s2, gsum, done);
    k_fused<<<dim3(NBLK), dim3(256), 0, stream>>>(
        Xh, Sh, x2, s2, w, gsum, done, out);
}

// Round 16
// 183.843 us; speedup vs baseline: 2.2784x; 1.1715x over previous
//
#include <hip/hip_runtime.h>
#include <hip/hip_bf16.h>
#include <math.h>

#define N_ROWS 65536
#define PSI    1024
#define DDIM   256

typedef _Float16       half8 __attribute__((ext_vector_type(8)));
typedef _Float16       half4 __attribute__((ext_vector_type(4)));
typedef float          f32x4 __attribute__((ext_vector_type(4)));

#define LOG2E 1.4426950408889634f

// ---------- async global->LDS, 16B per lane ----------
__device__ __forceinline__ void gload16(const void* g, void* l) {
    __builtin_amdgcn_global_load_lds(
        (const __attribute__((address_space(1))) unsigned int*)g,
        (__attribute__((address_space(3))) unsigned int*)l, 16, 0, 0);
}

// ---------- fused convert (X and S) + row norms + gsum init ----------
// blocks [0,16384): X rows; [16384,16640): S rows; block 16640: init gsum.
__global__ __launch_bounds__(256) void k_convert_all(
    const float* __restrict__ X, const float* __restrict__ S,
    _Float16* __restrict__ Xh, _Float16* __restrict__ Sh,
    float* __restrict__ x2, float* __restrict__ s2,
    float* __restrict__ gsum)
{
    const int bid = blockIdx.x;
    if (bid == 16640) {                      // re-init every call (graph replay)
        for (int i = threadIdx.x; i < PSI; i += 256) gsum[i] = 0.0f;
        return;
    }
    const float* in; _Float16* outh; float* nrm; int row;
    const int wib  = threadIdx.x >> 6;
    const int lane = threadIdx.x & 63;
    if (bid < 16384) { in = X; outh = Xh; nrm = x2; row = bid * 4 + wib; }
    else { in = S; outh = Sh; nrm = s2; row = (bid - 16384) * 4 + wib; }
    const float4 v = *(const float4*)&in[(size_t)row * DDIM + lane * 4];
    float s = v.x * v.x + v.y * v.y + v.z * v.z + v.w * v.w;
    #pragma unroll
    for (int o = 32; o > 0; o >>= 1) s += __shfl_down(s, o);
    if (lane == 0) nrm[row] = s;
    half4 h;
    h[0] = (_Float16)v.x; h[1] = (_Float16)v.y;
    h[2] = (_Float16)v.z; h[3] = (_Float16)v.w;
    *(half4*)&outh[(size_t)row * DDIM + lane * 4] = h;
}

// ---------- MFMA GEMM, 128x128 tile, BK=64, double-buffered (R6 verbatim) --
// Shift-free softmax: u = exp2(-sqrt(max(x2+s2-2dot,0))*w*log2e), u in
// [1e-13,1] -> no max-shift needed (f16 would flush; f32 path is exact).
// XCD-chunked 1D grid (4096): each XCD owns 64 row-panels x 8 col-blocks.
// LDS: [row][k] 128B rows, XOR-swizzle byte^=((row&7)<<4) applied as
// pre-swizzled GLOBAL k-chunk on stage + XOR'd ds_read (both-sides rule).
// MODE 0: column sums of u accumulated ATOMICALLY into gsum (no combine
//         kernels, no ps round-trip; float-atomic order wobble ~1 ulp).
// MODE 1: out = u / gsum[c]   (gsum L2-hot; nontemporal stream)
template<int MODE>
__global__ __launch_bounds__(256) void k_gemm(
    const _Float16* __restrict__ Xh, const _Float16* __restrict__ Sh,
    const float* __restrict__ x2, const float* __restrict__ s2,
    const float* __restrict__ w,
    float* __restrict__ gsum, float* __restrict__ out)
{
    __shared__ _Float16 As[2][128 * 64];   // 2 x 16 KB
    __shared__ _Float16 Bs[2][128 * 64];   // 2 x 16 KB

    const int tid  = threadIdx.x;
    const int wv   = tid >> 6;
    const int wr   = wv >> 1;       // wave row half (0..1)
    const int wc   = wv & 1;        // wave col half (0..1)
    const int l15  = tid & 15;
    const int l4   = (tid & 63) >> 4;

    // XCD swizzle (nwg=4096 divisible by 8 -> bijective)
    const int fid   = blockIdx.x;
    const int wgid  = (fid & 7) * 512 + (fid >> 3);
    const int rowb  = wgid >> 3;            // 0..511
    const int row0  = rowb * 128;
    const int col0  = (wgid & 7) * 128;

    f32x4 acc[4][4];
    #pragma unroll
    for (int i = 0; i < 4; ++i)
        #pragma unroll
        for (int j = 0; j < 4; ++j) acc[i][j] = (f32x4){0.f, 0.f, 0.f, 0.f};

    // staging: lane tid covers row tid>>3 (of 32-row group), pre-swizzled
    // k-chunk ((tid&7)^((tid>>3)&7))*8 halfs. 8 lanes cover one 128B row.
    const int srow = tid >> 3;
    const int skq  = ((tid & 7) ^ (srow & 7)) * 8;
    const _Float16* gAp = Xh + (size_t)(row0 + srow) * DDIM + skq;
    const _Float16* gBp = Sh + (size_t)(col0 + srow) * DDIM + skq;

    auto stage = [&](int k0, int b) {
        _Float16* Ab = &As[b][wv * 512];
        _Float16* Bb = &Bs[b][wv * 512];
        #pragma unroll
        for (int rg = 0; rg < 4; ++rg)
            gload16(gAp + (size_t)(rg * 32) * DDIM + k0, Ab + rg * 2048);
        #pragma unroll
        for (int rg = 0; rg < 4; ++rg)
            gload16(gBp + (size_t)(rg * 32) * DDIM + k0, Bb + rg * 2048);
    };

    auto compute = [&](int b) {
        #pragma unroll
        for (int kk = 0; kk < 2; ++kk) {
            half8 af[4], bf[4];
            #pragma unroll
            for (int f = 0; f < 4; ++f) {
                const int swz = (l15 & 7) << 3;               // halfs
                const int ha = ((wr * 64 + f * 16 + l15) * 64 + kk * 32 + l4 * 8) ^ swz;
                const int hb = ((wc * 64 + f * 16 + l15) * 64 + kk * 32 + l4 * 8) ^ swz;
                af[f] = *(const half8*)&As[b][ha];
                bf[f] = *(const half8*)&Bs[b][hb];
            }
            #pragma unroll
            for (int fm = 0; fm < 4; ++fm)
                #pragma unroll
                for (int fn = 0; fn < 4; ++fn)
                    acc[fm][fn] = __builtin_amdgcn_mfma_f32_16x16x32_f16(
                        af[fm], bf[fn], acc[fm][fn], 0, 0, 0);
        }
    };

    stage(0, 0);
    __syncthreads();
    #pragma unroll
    for (int t = 0; t < 4; ++t) {           // K = 4 x 64
        if (t < 3) stage((t + 1) * 64, (t + 1) & 1);
        compute(t & 1);
        if (t < 3) __syncthreads();
    }

    // ---- epilogue ----
    float4 x2r[4];
    #pragma unroll
    for (int fm = 0; fm < 4; ++fm)
        x2r[fm] = *(const float4*)&x2[row0 + wr * 64 + fm * 16 + l4 * 4];

    if (MODE == 0) {
        __syncthreads();                       // As dead -> alias sum array
        float* s_sm = (float*)&As[0][0];
        if (tid < 128) s_sm[tid] = 0.0f;
        __syncthreads();
        #pragma unroll
        for (int fn = 0; fn < 4; ++fn) {
            const int cl = wc * 64 + fn * 16 + l15;
            const int c  = col0 + cl;
            const float s2c = s2[c], ww2 = w[c] * LOG2E;
            float s = 0.0f;
            #pragma unroll
            for (int fm = 0; fm < 4; ++fm) {
                const float* xr = (const float*)&x2r[fm];
                #pragma unroll
                for (int j = 0; j < 4; ++j) {
                    float d2 = xr[j] + s2c - 2.0f * acc[fm][fn][j];
                    s += exp2f(-sqrtf(fmaxf(d2, 0.0f)) * ww2);
                }
            }
            // reduce over the 4 l4 row-groups (lane bits 4,5)
            s += __shfl_xor(s, 16);
            s += __shfl_xor(s, 32);
            if (l4 == 0) atomicAdd(&s_sm[cl], s);   // 2 waves (wr) contend
        }
        __syncthreads();
        if (tid < 128) atomicAdd(&gsum[col0 + tid], s_sm[tid]);
    } else {
        #pragma unroll
        for (int fn = 0; fn < 4; ++fn) {
            const int c = col0 + wc * 64 + fn * 16 + l15;
            const float s2c = s2[c], ww2 = w[c] * LOG2E;
            const float rsc = 1.0f / gsum[c];
            #pragma unroll
            for (int fm = 0; fm < 4; ++fm) {
                const float* xr = (const float*)&x2r[fm];
                const int rbase = row0 + wr * 64 + fm * 16 + l4 * 4;
                #pragma unroll
                for (int j = 0; j < 4; ++j) {
                    float d2 = xr[j] + s2c - 2.0f * acc[fm][fn][j];
                    float u  = exp2f(-sqrtf(fmaxf(d2, 0.0f)) * ww2) * rsc;
                    __builtin_nontemporal_store(u, &out[(size_t)(rbase + j) * PSI + c]);
                }
            }
        }
    }
}

extern "C" void kernel_launch(void* const* d_in, const int* in_sizes, int n_in,
                              void* d_out, int out_size, void* d_ws, size_t ws_size,
                              hipStream_t stream) {
    const float* X = (const float*)d_in[0];
    const float* S = (const float*)d_in[1];
    const float* w = (const float*)d_in[2];
    float* out = (float*)d_out;

    char* ws = (char*)d_ws;
    _Float16* Xh   = (_Float16*)(ws);                  // 33,554,432 B
    _Float16* Sh   = (_Float16*)(ws + 33554432);       //    524,288 B
    float*    x2   = (float*)   (ws + 34078720);       //    262,144 B
    float*    s2   = (float*)   (ws + 34340864);       //      4,096 B
    float*    gsum = (float*)   (ws + 34344960);       //      4,096 B

    k_convert_all<<<dim3(16641), dim3(256), 0, stream>>>(
        X, S, Xh, Sh, x2, s2, gsum);
    k_gemm<0><<<dim3(4096), dim3(256), 0, stream>>>(
        Xh, Sh, x2, s2, w, gsum, nullptr);
    k_gemm<1><<<dim3(4096), dim3(256), 0, stream>>>(
        Xh, Sh, x2, s2, w, gsum, out);
}

// Round 17
// 157.918 us; speedup vs baseline: 2.6524x; 1.1642x over previous
//
#include <hip/hip_runtime.h>
#include <hip/hip_bf16.h>
#include <math.h>

#define N_ROWS 65536
#define PSI    1024
#define DDIM   256

typedef _Float16       half8 __attribute__((ext_vector_type(8)));
typedef _Float16       half4 __attribute__((ext_vector_type(4)));
typedef float          f32x4 __attribute__((ext_vector_type(4)));

#define LOG2E 1.4426950408889634f

// Raw-instruction transcendentals: v_sqrt_f32 / v_exp_f32 / v_rcp_f32 are
// ~1-2 ulp (rel ~2e-7) -- negligible vs the 3.8e-6 f16-GEMM error floor.
// Default (non-fast-math) sqrtf/exp2f expand to IEEE sequences with ~6
// fixup ops each; at 134M sqrt+exp chains across both passes that is
// ~10-15us of pure VALU fat.
#if __has_builtin(__builtin_amdgcn_sqrtf)
#define FSQRT(x) __builtin_amdgcn_sqrtf(x)
#else
#define FSQRT(x) sqrtf(x)
#endif
#if __has_builtin(__builtin_amdgcn_exp2f)
#define FEXP2(x) __builtin_amdgcn_exp2f(x)
#else
#define FEXP2(x) exp2f(x)
#endif
#if __has_builtin(__builtin_amdgcn_rcpf)
#define FRCP(x) __builtin_amdgcn_rcpf(x)
#else
#define FRCP(x) (1.0f / (x))
#endif

// ---------- async global->LDS, 16B per lane ----------
__device__ __forceinline__ void gload16(const void* g, void* l) {
    __builtin_amdgcn_global_load_lds(
        (const __attribute__((address_space(1))) unsigned int*)g,
        (__attribute__((address_space(3))) unsigned int*)l, 16, 0, 0);
}

// ---------- fused convert (X and S) + row norms + gsum init ----------
// blocks [0,16384): X rows; [16384,16640): S rows; block 16640: init gsum.
// Source reads are nontemporal (read-once); Xh/Sh writes stay cached
// (re-read 8x by the GEMM passes).
__global__ __launch_bounds__(256) void k_convert_all(
    const float* __restrict__ X, const float* __restrict__ S,
    _Float16* __restrict__ Xh, _Float16* __restrict__ Sh,
    float* __restrict__ x2, float* __restrict__ s2,
    float* __restrict__ gsum)
{
    const int bid = blockIdx.x;
    if (bid == 16640) {                      // re-init every call (graph replay)
        for (int i = threadIdx.x; i < PSI; i += 256) gsum[i] = 0.0f;
        return;
    }
    const float* in; _Float16* outh; float* nrm; int row;
    const int wib  = threadIdx.x >> 6;
    const int lane = threadIdx.x & 63;
    if (bid < 16384) { in = X; outh = Xh; nrm = x2; row = bid * 4 + wib; }
    else { in = S; outh = Sh; nrm = s2; row = (bid - 16384) * 4 + wib; }
    const f32x4 v = __builtin_nontemporal_load(
        (const f32x4*)&in[(size_t)row * DDIM + lane * 4]);
    float s = v[0] * v[0] + v[1] * v[1] + v[2] * v[2] + v[3] * v[3];
    #pragma unroll
    for (int o = 32; o > 0; o >>= 1) s += __shfl_down(s, o);
    if (lane == 0) nrm[row] = s;
    half4 h;
    h[0] = (_Float16)v[0]; h[1] = (_Float16)v[1];
    h[2] = (_Float16)v[2]; h[3] = (_Float16)v[3];
    *(half4*)&outh[(size_t)row * DDIM + lane * 4] = h;
}

// ---------- MFMA GEMM, 128x128 tile, BK=64, double-buffered (R6 verbatim) --
// Shift-free softmax: u = exp2(-sqrt(max(x2+s2-2dot,0))*w*log2e), u in
// [1e-13,1] -> no max-shift needed (f16 would flush; f32 path is exact).
// XCD-chunked 1D grid (4096): each XCD owns 64 row-panels x 8 col-blocks.
// LDS: [row][k] 128B rows, XOR-swizzle byte^=((row&7)<<4) applied as
// pre-swizzled GLOBAL k-chunk on stage + XOR'd ds_read (both-sides rule).
// MODE 0: column sums of u accumulated ATOMICALLY into gsum (no combine
//         kernels, no ps round-trip; float-atomic order wobble ~1 ulp).
// MODE 1: out = u / gsum[c]   (gsum L2-hot; nontemporal stream)
template<int MODE>
__global__ __launch_bounds__(256) void k_gemm(
    const _Float16* __restrict__ Xh, const _Float16* __restrict__ Sh,
    const float* __restrict__ x2, const float* __restrict__ s2,
    const float* __restrict__ w,
    float* __restrict__ gsum, float* __restrict__ out)
{
    __shared__ _Float16 As[2][128 * 64];   // 2 x 16 KB
    __shared__ _Float16 Bs[2][128 * 64];   // 2 x 16 KB

    const int tid  = threadIdx.x;
    const int wv   = tid >> 6;
    const int wr   = wv >> 1;       // wave row half (0..1)
    const int wc   = wv & 1;        // wave col half (0..1)
    const int l15  = tid & 15;
    const int l4   = (tid & 63) >> 4;

    // XCD swizzle (nwg=4096 divisible by 8 -> bijective)
    const int fid   = blockIdx.x;
    const int wgid  = (fid & 7) * 512 + (fid >> 3);
    const int rowb  = wgid >> 3;            // 0..511
    const int row0  = rowb * 128;
    const int col0  = (wgid & 7) * 128;

    f32x4 acc[4][4];
    #pragma unroll
    for (int i = 0; i < 4; ++i)
        #pragma unroll
        for (int j = 0; j < 4; ++j) acc[i][j] = (f32x4){0.f, 0.f, 0.f, 0.f};

    // staging: lane tid covers row tid>>3 (of 32-row group), pre-swizzled
    // k-chunk ((tid&7)^((tid>>3)&7))*8 halfs. 8 lanes cover one 128B row.
    const int srow = tid >> 3;
    const int skq  = ((tid & 7) ^ (srow & 7)) * 8;
    const _Float16* gAp = Xh + (size_t)(row0 + srow) * DDIM + skq;
    const _Float16* gBp = Sh + (size_t)(col0 + srow) * DDIM + skq;

    auto stage = [&](int k0, int b) {
        _Float16* Ab = &As[b][wv * 512];
        _Float16* Bb = &Bs[b][wv * 512];
        #pragma unroll
        for (int rg = 0; rg < 4; ++rg)
            gload16(gAp + (size_t)(rg * 32) * DDIM + k0, Ab + rg * 2048);
        #pragma unroll
        for (int rg = 0; rg < 4; ++rg)
            gload16(gBp + (size_t)(rg * 32) * DDIM + k0, Bb + rg * 2048);
    };

    auto compute = [&](int b) {
        #pragma unroll
        for (int kk = 0; kk < 2; ++kk) {
            half8 af[4], bf[4];
            #pragma unroll
            for (int f = 0; f < 4; ++f) {
                const int swz = (l15 & 7) << 3;               // halfs
                const int ha = ((wr * 64 + f * 16 + l15) * 64 + kk * 32 + l4 * 8) ^ swz;
                const int hb = ((wc * 64 + f * 16 + l15) * 64 + kk * 32 + l4 * 8) ^ swz;
                af[f] = *(const half8*)&As[b][ha];
                bf[f] = *(const half8*)&Bs[b][hb];
            }
            #pragma unroll
            for (int fm = 0; fm < 4; ++fm)
                #pragma unroll
                for (int fn = 0; fn < 4; ++fn)
                    acc[fm][fn] = __builtin_amdgcn_mfma_f32_16x16x32_f16(
                        af[fm], bf[fn], acc[fm][fn], 0, 0, 0);
        }
    };

    stage(0, 0);
    __syncthreads();
    #pragma unroll
    for (int t = 0; t < 4; ++t) {           // K = 4 x 64
        if (t < 3) stage((t + 1) * 64, (t + 1) & 1);
        compute(t & 1);
        if (t < 3) __syncthreads();
    }

    // ---- epilogue ----
    float4 x2r[4];
    #pragma unroll
    for (int fm = 0; fm < 4; ++fm)
        x2r[fm] = *(const float4*)&x2[row0 + wr * 64 + fm * 16 + l4 * 4];

    if (MODE == 0) {
        __syncthreads();                       // As dead -> alias sum array
        float* s_sm = (float*)&As[0][0];
        if (tid < 128) s_sm[tid] = 0.0f;
        __syncthreads();
        #pragma unroll
        for (int fn = 0; fn < 4; ++fn) {
            const int cl = wc * 64 + fn * 16 + l15;
            const int c  = col0 + cl;
            const float s2c = s2[c], ww2 = w[c] * LOG2E;
            float s = 0.0f;
            #pragma unroll
            for (int fm = 0; fm < 4; ++fm) {
                const float* xr = (const float*)&x2r[fm];
                #pragma unroll
                for (int j = 0; j < 4; ++j) {
                    float d2 = xr[j] + s2c - 2.0f * acc[fm][fn][j];
                    s += FEXP2(-FSQRT(fmaxf(d2, 0.0f)) * ww2);
                }
            }
            // reduce over the 4 l4 row-groups (lane bits 4,5)
            s += __shfl_xor(s, 16);
            s += __shfl_xor(s, 32);
            if (l4 == 0) atomicAdd(&s_sm[cl], s);   // 2 waves (wr) contend
        }
        __syncthreads();
        if (tid < 128) atomicAdd(&gsum[col0 + tid], s_sm[tid]);
    } else {
        #pragma unroll
        for (int fn = 0; fn < 4; ++fn) {
            const int c = col0 + wc * 64 + fn * 16 + l15;
            const float s2c = s2[c], ww2 = w[c] * LOG2E;
            const float rsc = FRCP(gsum[c]);
            #pragma unroll
            for (int fm = 0; fm < 4; ++fm) {
                const float* xr = (const float*)&x2r[fm];
                const int rbase = row0 + wr * 64 + fm * 16 + l4 * 4;
                #pragma unroll
                for (int j = 0; j < 4; ++j) {
                    float d2 = xr[j] + s2c - 2.0f * acc[fm][fn][j];
                    float u  = FEXP2(-FSQRT(fmaxf(d2, 0.0f)) * ww2) * rsc;
                    __builtin_nontemporal_store(u, &out[(size_t)(rbase + j) * PSI + c]);
                }
            }
        }
    }
}

extern "C" void kernel_launch(void* const* d_in, const int* in_sizes, int n_in,
                              void* d_out, int out_size, void* d_ws, size_t ws_size,
                              hipStream_t stream) {
    const float* X = (const float*)d_in[0];
    const float* S = (const float*)d_in[1];
    const float* w = (const float*)d_in[2];
    float* out = (float*)d_out;

    char* ws = (char*)d_ws;
    _Float16* Xh   = (_Float16*)(ws);                  // 33,554,432 B
    _Float16* Sh   = (_Float16*)(ws + 33554432);       //    524,288 B
    float*    x2   = (float*)   (ws + 34078720);       //    262,144 B
    float*    s2   = (float*)   (ws + 34340864);       //      4,096 B
    float*    gsum = (float*)   (ws + 34344960);       //      4,096 B

    k_convert_all<<<dim3(16641), dim3(256), 0, stream>>>(
        X, S, Xh, Sh, x2, s2, gsum);
    k_gemm<0><<<dim3(4096), dim3(256), 0, stream>>>(
        Xh, Sh, x2, s2, w, gsum, nullptr);
    k_gemm<1><<<dim3(4096), dim3(256), 0, stream>>>(
        Xh, Sh, x2, s2, w, gsum, out);
}